// Round 3
// baseline (1463.270 us; speedup 1.0000x reference)
//
#include <hip/hip_runtime.h>
#include <hip/hip_bf16.h>

// GRU forward, T=512 B=256 I=H=256 fp32 in, fp32 [B,1] out.
// v3: (a) gru_step3 keeps ALL W_hh fragments in the unified VGPR/AGPR file
// (192 regs; launch_bounds(512,2) -> 256 cap) eliminating the 128KB/step LDS
// weight stream of v2; (b) gi is DMA'd one step ahead into LDS via
// global_load_lds (no VGPR cost, latency hidden); (c) gi layout is
// [t][bx][wave][lane][r8|z8|n8] so gemm stores and gru reads are dense
// 16B-per-lane; (d) gi_gemm4: 256 persistent blocks, full gate-triple weights
// per wave, 4-tile double-buffered staging, bias+exp2 scale folded at store.

#define TT 512
#define BB 256
#define II 256
#define HH 256

#define SRZ (-1.4426950408889634f)   // -log2(e): sigmoid(a) = rcp(1+exp2(SRZ*a))
#define SN  (2.8853900817779268f)    // 2*log2(e): tanh(y) = 1-2*rcp(1+exp2(SN*y))

typedef __attribute__((ext_vector_type(8))) short short8;
typedef __attribute__((ext_vector_type(4))) float f32x4;

__device__ __forceinline__ unsigned short rne_bf16(float f) {
  union { float f; unsigned u; } v; v.f = f;
  unsigned r = v.u + 0x7FFFu + ((v.u >> 16) & 1u);
  return (unsigned short)(r >> 16);
}
__device__ __forceinline__ float bf2f(unsigned short b) {
  union { unsigned u; float f; } v; v.u = ((unsigned)b) << 16;
  return v.f;
}
__device__ __forceinline__ float sigm(float x) { return 1.0f / (1.0f + __expf(-x)); }
__device__ __forceinline__ float tanhfast(float x) {
  return 1.0f - 2.0f / (__expf(2.0f * x) + 1.0f);
}

__device__ __forceinline__ short8 ldw8(const float* __restrict__ p) {
  float4 a = *reinterpret_cast<const float4*>(p);
  float4 b = *reinterpret_cast<const float4*>(p + 4);
  short8 r;
  r[0] = (short)rne_bf16(a.x); r[1] = (short)rne_bf16(a.y);
  r[2] = (short)rne_bf16(a.z); r[3] = (short)rne_bf16(a.w);
  r[4] = (short)rne_bf16(b.x); r[5] = (short)rne_bf16(b.y);
  r[6] = (short)rne_bf16(b.z); r[7] = (short)rne_bf16(b.w);
  return r;
}
__device__ __forceinline__ short8 ldw8s(const float* __restrict__ p, float s) {
  float4 a = *reinterpret_cast<const float4*>(p);
  float4 b = *reinterpret_cast<const float4*>(p + 4);
  short8 r;
  r[0] = (short)rne_bf16(a.x * s); r[1] = (short)rne_bf16(a.y * s);
  r[2] = (short)rne_bf16(a.z * s); r[3] = (short)rne_bf16(a.w * s);
  r[4] = (short)rne_bf16(b.x * s); r[5] = (short)rne_bf16(b.y * s);
  r[6] = (short)rne_bf16(b.z * s); r[7] = (short)rne_bf16(b.w * s);
  return r;
}

// swizzled [16][256] ushort LDS tile (reads measured ~conflict-free in v2)
#define SWZ(m, k) ((m) * 256 + ((k) ^ ((m) * 16)))

__device__ __forceinline__ short8 lda(const unsigned short* lds, int lane, int c) {
  int m = lane & 15;
  int k0 = c * 32 + (lane >> 4) * 8;
  return *reinterpret_cast<const short8*>(lds + SWZ(m, k0));
}

__device__ __forceinline__ f32x4 mfma16(short8 a, short8 b, f32x4 c) {
  return __builtin_amdgcn_mfma_f32_16x16x32_bf16(a, b, c, 0, 0, 0);
}

// async global->LDS, 16B per lane: lds dest = base + lane*16 (wave-uniform base)
__device__ __forceinline__ void gload_lds16(const void* g, void* lds) {
  __builtin_amdgcn_global_load_lds(
      (const __attribute__((address_space(1))) unsigned int*)g,
      (__attribute__((address_space(3))) unsigned int*)lds, 16, 0, 0);
}

// ---------------- Phase 1: gi = scale*(x @ W_ih^T + bias), packed -----------
// gi ushort layout: [tile = t*16+bx][wave(8)][lane(64)][24] where the 24 =
// [r:tl0 q0..3, tl1 q0..3][z: same][n: same]; r,z folded with (bih+bhh)*SRZ,
// n folded with bih*SN (bhh_n stays in gru since it multiplies by r).
__global__ __launch_bounds__(512, 2)
void gi_gemm4(const float* __restrict__ x, const float* __restrict__ Wih,
              const float* __restrict__ bih, const float* __restrict__ bhh,
              unsigned short* __restrict__ gi, int ntiles) {
  __shared__ unsigned short ax[2][4][4096];  // 2 buf x 4 tiles x 8KB = 64KB
  const int tid = threadIdx.x, l = tid & 63, w = tid >> 6;
  const int g4 = l >> 4, i15 = l & 15;

  short8 wf[3][2][8];
  float bs[3][2];
#pragma unroll
  for (int tl = 0; tl < 2; ++tl) {
    int j = 32 * w + 16 * tl + i15;
#pragma unroll
    for (int c = 0; c < 8; ++c) {
      int ko = c * 32 + g4 * 8;
      wf[0][tl][c] = ldw8s(Wih + (size_t)j * 256 + ko, SRZ);
      wf[1][tl][c] = ldw8s(Wih + (size_t)(256 + j) * 256 + ko, SRZ);
      wf[2][tl][c] = ldw8s(Wih + (size_t)(512 + j) * 256 + ko, SN);
    }
    bs[0][tl] = SRZ * (bih[j] + bhh[j]);
    bs[1][tl] = SRZ * (bih[256 + j] + bhh[256 + j]);
    bs[2][tl] = SN * bih[512 + j];
  }

  int tpb = ((ntiles + 255) >> 8);
  tpb = (tpb + 3) & ~3;                     // multiple of 4
  const int tstart = blockIdx.x * tpb;
  if (tstart >= ntiles) return;
  const int niter = tpb >> 2;

  auto stage4 = [&](int buf, int t0) {
#pragma unroll
    for (int p = 0; p < 8; ++p) {
      int f = p * 512 + tid;                // float4 index within 4-tile batch
      int tb = f >> 10, r4 = f & 1023;
      int m = r4 >> 6, k0 = (r4 & 63) << 2;
      int tsrc = t0 + tb; if (tsrc >= ntiles) tsrc = ntiles - 1;
      float4 v = *reinterpret_cast<const float4*>(x + (size_t)tsrc * 4096 + m * 256 + k0);
      ushort4 b;
      b.x = rne_bf16(v.x); b.y = rne_bf16(v.y);
      b.z = rne_bf16(v.z); b.w = rne_bf16(v.w);
      *reinterpret_cast<ushort4*>(&ax[buf][tb][SWZ(m, k0)]) = b;
    }
  };

  stage4(0, tstart);
  for (int it = 0; it < niter; ++it) {
    __syncthreads();
    if (it + 1 < niter) stage4((it + 1) & 1, tstart + (it + 1) * 4);
    const int cur = it & 1;
#pragma unroll
    for (int tb = 0; tb < 4; ++tb) {
      int tile = tstart + it * 4 + tb;
      if (tile >= ntiles) break;
      f32x4 acc[3][2];
#pragma unroll
      for (int g = 0; g < 3; ++g)
#pragma unroll
        for (int tl = 0; tl < 2; ++tl) acc[g][tl] = (f32x4){0, 0, 0, 0};
#pragma unroll
      for (int c = 0; c < 8; ++c) {
        short8 ah = lda(ax[cur][tb], l, c);
#pragma unroll
        for (int g = 0; g < 3; ++g) {
          acc[g][0] = mfma16(ah, wf[g][0][c], acc[g][0]);
          acc[g][1] = mfma16(ah, wf[g][1][c], acc[g][1]);
        }
      }
      unsigned short* gp = gi + (size_t)tile * 12288 + w * 1536 + l * 24;
#pragma unroll
      for (int g = 0; g < 3; ++g) {
        short8 o;
#pragma unroll
        for (int tl = 0; tl < 2; ++tl) {
#pragma unroll
          for (int q = 0; q < 4; ++q)
            o[tl * 4 + q] = (short)rne_bf16(acc[g][tl][q] + bs[g][tl]);
        }
        *reinterpret_cast<short8*>(gp + g * 8) = o;  // 16B dense per lane
      }
    }
  }
}

// ---------------- Phase 2: persistent GRU recurrence (v3) ----------------
__global__ __launch_bounds__(512, 2)
void gru_step3(const float* __restrict__ Whh, const float* __restrict__ bhh,
               const float* __restrict__ Wout, const float* __restrict__ bout,
               const unsigned short* __restrict__ gi, float* __restrict__ hchk,
               float* __restrict__ out, int t0, int nt) {
  __shared__ unsigned short hbuf[2][4096];    // 16KB h tiles (bf16, SWZ)
  __shared__ unsigned short gibuf[2][12288];  // 48KB gi double-buffer (DMA dest)
  __shared__ float hfin[4096];                // 16KB final h for projection
  const int tid = threadIdx.x, l = tid & 63, w = tid >> 6;
  const int g4 = l >> 4, i15 = l & 15;
  const int bx = blockIdx.x, b0 = bx * 16;

  // All W_hh fragments resident: 3 gates x 2 col-tiles x 8 chunks = 192 regs
  short8 wf[3][2][8];
  float cn[2];
#pragma unroll
  for (int tl = 0; tl < 2; ++tl) {
    int j = 32 * w + 16 * tl + i15;
#pragma unroll
    for (int c = 0; c < 8; ++c) {
      int ko = c * 32 + g4 * 8;
      wf[0][tl][c] = ldw8s(Whh + (size_t)j * 256 + ko, SRZ);
      wf[1][tl][c] = ldw8s(Whh + (size_t)(256 + j) * 256 + ko, SRZ);
      wf[2][tl][c] = ldw8s(Whh + (size_t)(512 + j) * 256 + ko, SN);
    }
    cn[tl] = SN * bhh[512 + j];
  }

  f32x4 h[2] = {{0, 0, 0, 0}, {0, 0, 0, 0}};
  if (t0 == 0) {
    for (int i = tid; i < 4096; i += 512) hbuf[0][i] = 0;
  } else {
#pragma unroll
    for (int tl = 0; tl < 2; ++tl) {
      int j = 32 * w + 16 * tl + i15;
#pragma unroll
      for (int q = 0; q < 4; ++q) {
        float hv = hchk[(size_t)(b0 + 4 * g4 + q) * 256 + j];
        h[tl][q] = hv;
        hbuf[0][SWZ(4 * g4 + q, j)] = rne_bf16(hv);
      }
    }
  }

  // gi DMA source: per-lane 48B = [r8|z8|n8]; advance 393216B per step
  const char* gsrc = (const char*)gi + (size_t)bx * 24576 + w * 3072 + (size_t)l * 48;
  // prologue: DMA step-0 gi into gibuf[0]
#pragma unroll
  for (int k = 0; k < 3; ++k)
    gload_lds16(gsrc + k * 16, &gibuf[0][w * 1536 + k * 512]);
  __syncthreads();  // drains DMA (vmcnt) + hbuf init visible

  for (int lt = 0; lt < nt; ++lt) {
    const int cur = lt & 1, nxt = cur ^ 1;
    // issue next step's gi DMA (re-reads last step when lt==nt-1; unused)
    if (lt + 1 < nt) gsrc += 393216;
#pragma unroll
    for (int k = 0; k < 3; ++k)
      gload_lds16(gsrc + k * 16, &gibuf[nxt][w * 1536 + k * 512]);

    // MFMA phase: 48 MFMAs from resident weights
    f32x4 aR[2] = {{0, 0, 0, 0}, {0, 0, 0, 0}};
    f32x4 aZ[2] = {{0, 0, 0, 0}, {0, 0, 0, 0}};
    f32x4 aN[2] = {{0, 0, 0, 0}, {0, 0, 0, 0}};
    const unsigned short* hb = hbuf[cur];
#pragma unroll
    for (int c = 0; c < 8; ++c) {
      short8 ah = lda(hb, l, c);
      aR[0] = mfma16(ah, wf[0][0][c], aR[0]);
      aR[1] = mfma16(ah, wf[0][1][c], aR[1]);
      aZ[0] = mfma16(ah, wf[1][0][c], aZ[0]);
      aZ[1] = mfma16(ah, wf[1][1][c], aZ[1]);
      aN[0] = mfma16(ah, wf[2][0][c], aN[0]);
      aN[1] = mfma16(ah, wf[2][1][c], aN[1]);
    }

    // gi readback (landed before the barrier we crossed)
    const unsigned short* gb = &gibuf[cur][w * 1536 + l * 8];
    short8 gR = *reinterpret_cast<const short8*>(gb);
    short8 gZ = *reinterpret_cast<const short8*>(gb + 512);
    short8 gN = *reinterpret_cast<const short8*>(gb + 1024);

    unsigned short* hw = hbuf[nxt];
#pragma unroll
    for (int tl = 0; tl < 2; ++tl) {
      int jx = 32 * w + 16 * tl + i15;
#pragma unroll
      for (int q = 0; q < 4; ++q) {
        float gr = bf2f((unsigned short)gR[tl * 4 + q]);
        float gz = bf2f((unsigned short)gZ[tl * 4 + q]);
        float gv = bf2f((unsigned short)gN[tl * 4 + q]);
        float r  = __builtin_amdgcn_rcpf(1.0f + __builtin_amdgcn_exp2f(aR[tl][q] + gr));
        float zz = __builtin_amdgcn_rcpf(1.0f + __builtin_amdgcn_exp2f(aZ[tl][q] + gz));
        float y  = gv + r * (aN[tl][q] + cn[tl]);
        float nn = 1.0f - 2.0f * __builtin_amdgcn_rcpf(1.0f + __builtin_amdgcn_exp2f(y));
        float hq = nn + zz * (h[tl][q] - nn);
        h[tl][q] = hq;
        hw[SWZ(4 * g4 + q, jx)] = rne_bf16(hq);
      }
    }
    __syncthreads();  // h(t+1) + next gi visible; prev reads done
  }

  if (t0 + nt < TT) {
#pragma unroll
    for (int tl = 0; tl < 2; ++tl) {
      int j = 32 * w + 16 * tl + i15;
#pragma unroll
      for (int q = 0; q < 4; ++q)
        hchk[(size_t)(b0 + 4 * g4 + q) * 256 + j] = h[tl][q];
    }
  } else {
#pragma unroll
    for (int tl = 0; tl < 2; ++tl) {
      int j = 32 * w + 16 * tl + i15;
#pragma unroll
      for (int q = 0; q < 4; ++q) hfin[(4 * g4 + q) * 256 + j] = h[tl][q];
    }
    __syncthreads();
#pragma unroll
    for (int rr = 0; rr < 2; ++rr) {
      int r = 2 * w + rr;
      float s = 0.0f;
#pragma unroll
      for (int i = 0; i < 4; ++i) {
        int k = l + 64 * i;
        s += hfin[r * 256 + k] * Wout[k];
      }
#pragma unroll
      for (int off = 32; off > 0; off >>= 1) s += __shfl_xor(s, off, 64);
      if (l == 0) out[b0 + r] = sigm(s + bout[0]);
    }
  }
}

// ---------------- Fused fallback (used only if ws too small) ------------
__global__ __launch_bounds__(1024, 1) void gru_fused_legacy(
    const float* __restrict__ x, const float* __restrict__ Wih,
    const float* __restrict__ Whh, const float* __restrict__ bih,
    const float* __restrict__ bhh, const float* __restrict__ Wout,
    const float* __restrict__ bout, float* __restrict__ out) {
  __shared__ unsigned short hbuf[2][16 * 256];
  __shared__ unsigned short xbuf[2][16 * 256];
  __shared__ float hfin[16][256];
  int tid = threadIdx.x, lane = tid & 63, w = tid >> 6;
  int i15 = lane & 15, g4 = lane >> 4;
  int b0 = blockIdx.x * 16;
  int j = 16 * w + i15;

  short8 whh0[8], whh1[8], whh2[8], wih0[8], wih1[8], wih2[8];
#pragma unroll
  for (int c = 0; c < 8; ++c) {
    int ko = c * 32 + g4 * 8;
    whh0[c] = ldw8(Whh + (size_t)j * 256 + ko);
    whh1[c] = ldw8(Whh + (size_t)(256 + j) * 256 + ko);
    whh2[c] = ldw8(Whh + (size_t)(512 + j) * 256 + ko);
    wih0[c] = ldw8(Wih + (size_t)j * 256 + ko);
    wih1[c] = ldw8(Wih + (size_t)(256 + j) * 256 + ko);
    wih2[c] = ldw8(Wih + (size_t)(512 + j) * 256 + ko);
  }
  float bias_r = bih[j] + bhh[j];
  float bias_z = bih[256 + j] + bhh[256 + j];
  float bihn = bih[512 + j], bhhn = bhh[512 + j];

  f32x4 h = {0, 0, 0, 0};
  for (int idx = tid; idx < 16 * 256; idx += 1024) hbuf[0][idx] = 0;
  {
    int m = tid >> 6, k0 = (tid & 63) << 2;
    float4 v = *reinterpret_cast<const float4*>(x + (size_t)b0 * II + m * 256 + k0);
    ushort4 b;
    b.x = rne_bf16(v.x); b.y = rne_bf16(v.y);
    b.z = rne_bf16(v.z); b.w = rne_bf16(v.w);
    *reinterpret_cast<ushort4*>(&xbuf[0][SWZ(m, k0)]) = b;
  }
  __syncthreads();

  for (int lt = 0; lt < TT; ++lt) {
    int cur = lt & 1, nxt = cur ^ 1;
    short8 ah[8], axf[8];
#pragma unroll
    for (int c = 0; c < 8; ++c) ah[c] = lda(hbuf[cur], lane, c);
#pragma unroll
    for (int c = 0; c < 8; ++c) axf[c] = lda(xbuf[cur], lane, c);
    f32x4 gr = {0, 0, 0, 0}, gz = {0, 0, 0, 0}, gn = {0, 0, 0, 0};
    f32x4 ar = {0, 0, 0, 0}, az = {0, 0, 0, 0}, an = {0, 0, 0, 0};
#pragma unroll
    for (int c = 0; c < 8; ++c) {
      gr = mfma16(axf[c], wih0[c], gr);
      gz = mfma16(axf[c], wih1[c], gz);
      gn = mfma16(axf[c], wih2[c], gn);
    }
    if (lt + 1 < TT) {
      int m = tid >> 6, k0 = (tid & 63) << 2;
      float4 v = *reinterpret_cast<const float4*>(
          x + ((size_t)(lt + 1) * BB + b0) * II + m * 256 + k0);
      ushort4 b;
      b.x = rne_bf16(v.x); b.y = rne_bf16(v.y);
      b.z = rne_bf16(v.z); b.w = rne_bf16(v.w);
      *reinterpret_cast<ushort4*>(&xbuf[nxt][SWZ(m, k0)]) = b;
    }
#pragma unroll
    for (int c = 0; c < 8; ++c) {
      ar = mfma16(ah[c], whh0[c], ar);
      az = mfma16(ah[c], whh1[c], az);
      an = mfma16(ah[c], whh2[c], an);
    }
#pragma unroll
    for (int q = 0; q < 4; ++q) {
      float r = sigm(ar[q] + gr[q] + bias_r);
      float zz = sigm(az[q] + gz[q] + bias_z);
      float nn = tanhfast(gn[q] + bihn + r * (an[q] + bhhn));
      float hq = (1.0f - zz) * nn + zz * h[q];
      h[q] = hq;
      hbuf[nxt][SWZ(g4 * 4 + q, j)] = rne_bf16(hq);
    }
    __syncthreads();
  }
#pragma unroll
  for (int q = 0; q < 4; ++q) hfin[g4 * 4 + q][j] = h[q];
  __syncthreads();
  float s = 0.0f;
#pragma unroll
  for (int i = 0; i < 4; ++i) {
    int k = lane + 64 * i;
    s += hfin[w][k] * Wout[k];
  }
#pragma unroll
  for (int off = 32; off > 0; off >>= 1) s += __shfl_xor(s, off, 64);
  if (lane == 0) out[b0 + w] = sigm(s + bout[0]);
}

extern "C" void kernel_launch(void* const* d_in, const int* in_sizes, int n_in,
                              void* d_out, int out_size, void* d_ws, size_t ws_size,
                              hipStream_t stream) {
  const float* x    = (const float*)d_in[0];
  const float* Wih  = (const float*)d_in[1];
  const float* Whh  = (const float*)d_in[2];
  const float* bih  = (const float*)d_in[3];
  const float* bhh  = (const float*)d_in[4];
  const float* Wout = (const float*)d_in[5];
  const float* bout = (const float*)d_in[6];
  float* out = (float*)d_out;

  const size_t HBYTES = (size_t)BB * HH * sizeof(float);                  // 256 KB
  const size_t STEP_BYTES = (size_t)16 * 12288 * sizeof(unsigned short);  // 384 KB/t
  size_t gi_cap = ws_size > HBYTES ? ws_size - HBYTES : 0;
  long tc = (long)(gi_cap / STEP_BYTES);
  if (tc > TT) tc = TT;

  if (tc >= 32) {
    float* hchk = (float*)d_ws;
    unsigned short* gi = (unsigned short*)((char*)d_ws + HBYTES);
    for (int t0 = 0; t0 < TT; t0 += (int)tc) {
      int nt = (TT - t0) < (int)tc ? (TT - t0) : (int)tc;
      gi_gemm4<<<dim3(256), dim3(512), 0, stream>>>(
          x + (size_t)t0 * BB * II, Wih, bih, bhh, gi, nt * 16);
      gru_step3<<<dim3(16), dim3(512), 0, stream>>>(
          Whh, bhh, Wout, bout, gi, hchk, out, t0, nt);
    }
  } else {
    gru_fused_legacy<<<dim3(16), dim3(1024), 0, stream>>>(
        x, Wih, Whh, bih, bhh, Wout, bout, out);
  }
}

// Round 4
// 1219.871 us; speedup vs baseline: 1.1995x; 1.1995x over previous
//
#include <hip/hip_runtime.h>
#include <hip/hip_bf16.h>

// GRU forward, T=512 B=256 I=H=256 fp32 in, fp32 [B,1] out.
// v4: scale the recurrence out to 128 CUs (2 batch rows/block) instead of 16.
//  - gru_step4: 128 blocks x 256 thr (4 waves, waves_per_eu(1,1) -> 512-reg
//    budget). ALL W_hh fragments resident (384 regs/lane, no spill headroom
//    issues). A-operand = h broadcast from a 1KB XOR-swizzled LDS buffer.
//    MFMA outputs redistributed in-wave via small LDS scratch so each lane
//    owns one H-column (r,z,n x 2 rows) -> transcendental work spread over
//    all 64 lanes AND 128 CUs. gi read as 3 coalesced dword register loads
//    per lane per step (pre-distributed layout; no global_load_lds, so no
//    vmcnt(0)-at-barrier drain of a 24KB DMA).
//  - gi_gemm5: 256 blocks x 256 thr, 384 resident weight regs, 4-tile
//    double-buffered staging, stores gi directly in the gru's distributed
//    layout with biases and exp2-scales folded in.

#define TT 512
#define BB 256
#define II 256
#define HH 256

#define SRZ (-1.4426950408889634f)   // -log2(e): sigmoid(a) = rcp(1+exp2(SRZ*a))
#define SN  (2.8853900817779268f)    // 2*log2(e): tanh(y) = 1-2*rcp(1+exp2(SN*y))

typedef __attribute__((ext_vector_type(8))) short short8;
typedef __attribute__((ext_vector_type(4))) float f32x4;

__device__ __forceinline__ unsigned short rne_bf16(float f) {
  union { float f; unsigned u; } v; v.f = f;
  unsigned r = v.u + 0x7FFFu + ((v.u >> 16) & 1u);
  return (unsigned short)(r >> 16);
}
__device__ __forceinline__ float bf2f(unsigned short b) {
  union { unsigned u; float f; } v; v.u = ((unsigned)b) << 16;
  return v.f;
}
__device__ __forceinline__ float sigm(float x) { return 1.0f / (1.0f + __expf(-x)); }
__device__ __forceinline__ float tanhfast(float x) {
  return 1.0f - 2.0f / (__expf(2.0f * x) + 1.0f);
}

__device__ __forceinline__ short8 ldw8(const float* __restrict__ p) {
  float4 a = *reinterpret_cast<const float4*>(p);
  float4 b = *reinterpret_cast<const float4*>(p + 4);
  short8 r;
  r[0] = (short)rne_bf16(a.x); r[1] = (short)rne_bf16(a.y);
  r[2] = (short)rne_bf16(a.z); r[3] = (short)rne_bf16(a.w);
  r[4] = (short)rne_bf16(b.x); r[5] = (short)rne_bf16(b.y);
  r[6] = (short)rne_bf16(b.z); r[7] = (short)rne_bf16(b.w);
  return r;
}
__device__ __forceinline__ short8 ldw8s(const float* __restrict__ p, float s) {
  float4 a = *reinterpret_cast<const float4*>(p);
  float4 b = *reinterpret_cast<const float4*>(p + 4);
  short8 r;
  r[0] = (short)rne_bf16(a.x * s); r[1] = (short)rne_bf16(a.y * s);
  r[2] = (short)rne_bf16(a.z * s); r[3] = (short)rne_bf16(a.w * s);
  r[4] = (short)rne_bf16(b.x * s); r[5] = (short)rne_bf16(b.y * s);
  r[6] = (short)rne_bf16(b.z * s); r[7] = (short)rne_bf16(b.w * s);
  return r;
}

// 16-row staged x tile (gemm): swizzled [16][256] ushort
#define SWZ(m, k) ((m) * 256 + ((k) ^ ((m) * 16)))

__device__ __forceinline__ f32x4 mfma16(short8 a, short8 b, f32x4 c) {
  return __builtin_amdgcn_mfma_f32_16x16x32_bf16(a, b, c, 0, 0, 0);
}

// ---------------- Phase 1: gi = scale*(x @ W_ih^T + bias), distributed ------
// gi dword layout: [(tt*128 + bx)*3 + gate]*256 + col ; dword = (brow0|brow1<<16)
// where bx = b>>1, brow = b&1, col = H-column. Values pre-scaled by SRZ/SN and
// biases folded (r,z: bih+bhh; n: bih only).
__global__ __launch_bounds__(256)
__attribute__((amdgpu_waves_per_eu(1, 1)))
void gi_gemm5(const float* __restrict__ x, const float* __restrict__ Wih,
              const float* __restrict__ bih, const float* __restrict__ bhh,
              unsigned int* __restrict__ gi, int ntiles) {
  __shared__ unsigned short ax[2][4][4096];  // 2 buf x 4 tiles x 8KB = 64KB
  const int tid = threadIdx.x, l = tid & 63, w = tid >> 6;
  const int g4 = l >> 4, i15 = l & 15;

  // resident weights: 3 gates x 4 col-tiles x 8 k-chunks = 96 short8 = 384 regs
  short8 wf[3][4][8];
  float bs[3][4];
#pragma unroll
  for (int g = 0; g < 3; ++g)
#pragma unroll
    for (int t4 = 0; t4 < 4; ++t4) {
      int j = 64 * w + 16 * t4 + i15;
      float s = (g == 2) ? SN : SRZ;
#pragma unroll
      for (int c = 0; c < 8; ++c)
        wf[g][t4][c] = ldw8s(Wih + (size_t)(g * 256 + j) * 256 + c * 32 + g4 * 8, s);
      bs[g][t4] = (g == 2) ? SN * bih[512 + j]
                           : SRZ * (bih[g * 256 + j] + bhh[g * 256 + j]);
    }

  int tpb = (ntiles + 255) >> 8;
  tpb = (tpb + 3) & ~3;
  const int tstart = blockIdx.x * tpb;
  if (tstart >= ntiles) return;
  const int niter = tpb >> 2;

  auto stage4 = [&](int buf, int t0) {
#pragma unroll 1
    for (int grp = 0; grp < 4; ++grp) {
      float4 v[4];
      int tb_[4], m_[4], k0_[4];
#pragma unroll
      for (int u = 0; u < 4; ++u) {
        int f = (grp * 4 + u) * 256 + tid;
        tb_[u] = f >> 10;
        int r4 = f & 1023;
        m_[u] = r4 >> 6; k0_[u] = (r4 & 63) << 2;
        int tsrc = t0 + tb_[u]; if (tsrc >= ntiles) tsrc = ntiles - 1;
        v[u] = *reinterpret_cast<const float4*>(
            x + (size_t)tsrc * 4096 + m_[u] * 256 + k0_[u]);
      }
#pragma unroll
      for (int u = 0; u < 4; ++u) {
        ushort4 b;
        b.x = rne_bf16(v[u].x); b.y = rne_bf16(v[u].y);
        b.z = rne_bf16(v[u].z); b.w = rne_bf16(v[u].w);
        *reinterpret_cast<ushort4*>(&ax[buf][tb_[u]][SWZ(m_[u], k0_[u])]) = b;
      }
    }
  };

  stage4(0, tstart);
  for (int it = 0; it < niter; ++it) {
    __syncthreads();
    if (it + 1 < niter) stage4((it + 1) & 1, tstart + (it + 1) * 4);
    const int cur = it & 1;
#pragma unroll 1
    for (int tb = 0; tb < 4; ++tb) {
      int tile = tstart + it * 4 + tb;
      if (tile >= ntiles) break;
      f32x4 acc[3][4];
#pragma unroll
      for (int g = 0; g < 3; ++g)
#pragma unroll
        for (int t4 = 0; t4 < 4; ++t4) acc[g][t4] = (f32x4){0, 0, 0, 0};
#pragma unroll
      for (int c = 0; c < 8; ++c) {
        int m = l & 15, k0 = c * 32 + g4 * 8;
        short8 ah = *reinterpret_cast<const short8*>(&ax[cur][tb][SWZ(m, k0)]);
#pragma unroll
        for (int g = 0; g < 3; ++g)
#pragma unroll
          for (int t4 = 0; t4 < 4; ++t4)
            acc[g][t4] = mfma16(ah, wf[g][t4][c], acc[g][t4]);
      }
      int tt = tile >> 4, bhi = tile & 15;
#pragma unroll
      for (int g = 0; g < 3; ++g)
#pragma unroll
        for (int t4 = 0; t4 < 4; ++t4)
#pragma unroll
          for (int qh = 0; qh < 2; ++qh) {
            int bx2 = bhi * 8 + 2 * g4 + qh;
            size_t off = ((size_t)(tt * 128 + bx2) * 3 + g) * 256 +
                         (64 * w + 16 * t4 + i15);
            unsigned lo = rne_bf16(acc[g][t4][2 * qh] + bs[g][t4]);
            unsigned hi = rne_bf16(acc[g][t4][2 * qh + 1] + bs[g][t4]);
            gi[off] = lo | (hi << 16);
          }
    }
  }
}

// ---------------- Phase 2: persistent GRU recurrence (v4) ----------------
// 128 blocks x 256 thr; block bx owns batch rows {2bx, 2bx+1}. Each lane owns
// one H-column cstar = 64*w + l (r,z,n for both rows).
__global__ __launch_bounds__(256)
__attribute__((amdgpu_waves_per_eu(1, 1)))
void gru_step4(const float* __restrict__ Whh, const float* __restrict__ bhh,
               const float* __restrict__ Wout, const float* __restrict__ bout,
               const unsigned int* __restrict__ gi, float* __restrict__ hchk,
               float* __restrict__ out, int t0, int nt) {
  __shared__ unsigned short hbuf[2][2][256];  // [buf][row][col^(row*8)] bf16
  __shared__ float2 pscr[4][3][64];           // in-wave redistribution scratch
  __shared__ float pacc[4][2][64];            // final projection partials
  const int tid = threadIdx.x, l = tid & 63, w = tid >> 6;
  const int g4 = l >> 4, i15 = l & 15;
  const int bx = blockIdx.x;
  const int cstar = 64 * w + l;

  // resident weights: 384 regs/lane
  short8 wf[3][4][8];
#pragma unroll
  for (int g = 0; g < 3; ++g)
#pragma unroll
    for (int t4 = 0; t4 < 4; ++t4) {
      int j = 64 * w + 16 * t4 + i15;
      float s = (g == 2) ? SN : SRZ;
#pragma unroll
      for (int c = 0; c < 8; ++c)
        wf[g][t4][c] = ldw8s(Whh + (size_t)(g * 256 + j) * 256 + c * 32 + g4 * 8, s);
    }
  const float cn = SN * bhh[512 + cstar];
  const float wo = Wout[cstar];

  float h0, h1;
  if (t0 == 0) {
    h0 = 0.0f; h1 = 0.0f;
    ((unsigned short*)hbuf[0])[tid] = 0;
    ((unsigned short*)hbuf[0])[tid + 256] = 0;
  } else {
    h0 = hchk[(size_t)(2 * bx + 0) * 256 + cstar];
    h1 = hchk[(size_t)(2 * bx + 1) * 256 + cstar];
    hbuf[0][0][cstar] = rne_bf16(h0);
    hbuf[0][1][cstar ^ 8] = rne_bf16(h1);
  }
  __syncthreads();

  // current-step gi (3 coalesced dwords/lane)
  size_t gb = ((size_t)0 * 128 + bx) * 768;
  unsigned gR = gi[gb + cstar], gZ = gi[gb + 256 + cstar], gN = gi[gb + 512 + cstar];

  for (int lt = 0; lt < nt; ++lt) {
    const int cur = lt & 1, nxt = cur ^ 1;
    // prefetch next step's gi into registers (consumed after the barrier)
    unsigned nR = 0, nZ = 0, nN = 0;
    if (lt + 1 < nt) {
      size_t nb = ((size_t)(lt + 1) * 128 + bx) * 768;
      nR = gi[nb + cstar]; nZ = gi[nb + 256 + cstar]; nN = gi[nb + 512 + cstar];
    }

    // MFMA: 96 per wave, A = broadcast h rows (2 real)
    f32x4 acc[3][4];
#pragma unroll
    for (int g = 0; g < 3; ++g)
#pragma unroll
      for (int t4 = 0; t4 < 4; ++t4) acc[g][t4] = (f32x4){0, 0, 0, 0};
    const unsigned short* hb = &hbuf[cur][0][0];
    const int m2 = l & 1;
#pragma unroll
    for (int c = 0; c < 8; ++c) {
      int k0 = c * 32 + g4 * 8;
      short8 ah = *reinterpret_cast<const short8*>(hb + m2 * 256 + (k0 ^ (m2 * 8)));
#pragma unroll
      for (int g = 0; g < 3; ++g)
#pragma unroll
        for (int t4 = 0; t4 < 4; ++t4)
          acc[g][t4] = mfma16(ah, wf[g][t4][c], acc[g][t4]);
    }

    // in-wave redistribution: lanes 0-15 hold rows 0,1 of all 12 tiles;
    // after this, lane l owns column cstar for all 3 gates.
    if (l < 16) {
#pragma unroll
      for (int g = 0; g < 3; ++g)
#pragma unroll
        for (int t4 = 0; t4 < 4; ++t4)
          pscr[w][g][16 * t4 + i15] = make_float2(acc[g][t4][0], acc[g][t4][1]);
    }
    float2 vR = pscr[w][0][l];
    float2 vZ = pscr[w][1][l];
    float2 vN = pscr[w][2][l];

    // combine (one column, two batch rows)
    {
      float r0 = __builtin_amdgcn_rcpf(
          1.0f + __builtin_amdgcn_exp2f(vR.x + bf2f((unsigned short)(gR & 0xffff))));
      float z0 = __builtin_amdgcn_rcpf(
          1.0f + __builtin_amdgcn_exp2f(vZ.x + bf2f((unsigned short)(gZ & 0xffff))));
      float y0 = bf2f((unsigned short)(gN & 0xffff)) + r0 * (vN.x + cn);
      float n0 = 1.0f - 2.0f * __builtin_amdgcn_rcpf(1.0f + __builtin_amdgcn_exp2f(y0));
      h0 = n0 + z0 * (h0 - n0);
      float r1 = __builtin_amdgcn_rcpf(
          1.0f + __builtin_amdgcn_exp2f(vR.y + bf2f((unsigned short)(gR >> 16))));
      float z1 = __builtin_amdgcn_rcpf(
          1.0f + __builtin_amdgcn_exp2f(vZ.y + bf2f((unsigned short)(gZ >> 16))));
      float y1 = bf2f((unsigned short)(gN >> 16)) + r1 * (vN.y + cn);
      float n1 = 1.0f - 2.0f * __builtin_amdgcn_rcpf(1.0f + __builtin_amdgcn_exp2f(y1));
      h1 = n1 + z1 * (h1 - n1);
    }
    hbuf[nxt][0][cstar] = rne_bf16(h0);
    hbuf[nxt][1][cstar ^ 8] = rne_bf16(h1);
    gR = nR; gZ = nZ; gN = nN;
    __syncthreads();
  }

  if (t0 + nt < TT) {
    hchk[(size_t)(2 * bx + 0) * 256 + cstar] = h0;
    hchk[(size_t)(2 * bx + 1) * 256 + cstar] = h1;
  } else {
    pacc[w][0][l] = h0 * wo;
    pacc[w][1][l] = h1 * wo;
    __syncthreads();
    if (w == 0) {
#pragma unroll
      for (int p = 0; p < 2; ++p) {
        float s = pacc[0][p][l] + pacc[1][p][l] + pacc[2][p][l] + pacc[3][p][l];
#pragma unroll
        for (int off = 32; off > 0; off >>= 1) s += __shfl_xor(s, off, 64);
        if (l == 0) out[2 * bx + p] = sigm(s + bout[0]);
      }
    }
  }
}

// ---------------- Fused fallback (used only if ws too small) ------------
__global__ __launch_bounds__(1024, 1) void gru_fused_legacy(
    const float* __restrict__ x, const float* __restrict__ Wih,
    const float* __restrict__ Whh, const float* __restrict__ bih,
    const float* __restrict__ bhh, const float* __restrict__ Wout,
    const float* __restrict__ bout, float* __restrict__ out) {
  __shared__ unsigned short hbuf[2][16 * 256];
  __shared__ unsigned short xbuf[2][16 * 256];
  __shared__ float hfin[16][256];
  int tid = threadIdx.x, lane = tid & 63, w = tid >> 6;
  int i15 = lane & 15, g4 = lane >> 4;
  int b0 = blockIdx.x * 16;
  int j = 16 * w + i15;

  short8 whh0[8], whh1[8], whh2[8], wih0[8], wih1[8], wih2[8];
#pragma unroll
  for (int c = 0; c < 8; ++c) {
    int ko = c * 32 + g4 * 8;
    whh0[c] = ldw8(Whh + (size_t)j * 256 + ko);
    whh1[c] = ldw8(Whh + (size_t)(256 + j) * 256 + ko);
    whh2[c] = ldw8(Whh + (size_t)(512 + j) * 256 + ko);
    wih0[c] = ldw8(Wih + (size_t)j * 256 + ko);
    wih1[c] = ldw8(Wih + (size_t)(256 + j) * 256 + ko);
    wih2[c] = ldw8(Wih + (size_t)(512 + j) * 256 + ko);
  }
  float bias_r = bih[j] + bhh[j];
  float bias_z = bih[256 + j] + bhh[256 + j];
  float bihn = bih[512 + j], bhhn = bhh[512 + j];

  f32x4 h = {0, 0, 0, 0};
  for (int idx = tid; idx < 16 * 256; idx += 1024) hbuf[0][idx] = 0;
  {
    int m = tid >> 6, k0 = (tid & 63) << 2;
    float4 v = *reinterpret_cast<const float4*>(x + (size_t)b0 * II + m * 256 + k0);
    ushort4 b;
    b.x = rne_bf16(v.x); b.y = rne_bf16(v.y);
    b.z = rne_bf16(v.z); b.w = rne_bf16(v.w);
    *reinterpret_cast<ushort4*>(&xbuf[0][SWZ(m, k0)]) = b;
  }
  __syncthreads();

  for (int lt = 0; lt < TT; ++lt) {
    int cur = lt & 1, nxt = cur ^ 1;
    short8 ah[8], axf[8];
#pragma unroll
    for (int c = 0; c < 8; ++c) {
      int m = lane & 15, k0 = c * 32 + g4 * 8;
      ah[c] = *reinterpret_cast<const short8*>(&hbuf[cur][SWZ(m, k0)]);
      axf[c] = *reinterpret_cast<const short8*>(&xbuf[cur][SWZ(m, k0)]);
    }
    f32x4 gr = {0, 0, 0, 0}, gz = {0, 0, 0, 0}, gn = {0, 0, 0, 0};
    f32x4 ar = {0, 0, 0, 0}, az = {0, 0, 0, 0}, an = {0, 0, 0, 0};
#pragma unroll
    for (int c = 0; c < 8; ++c) {
      gr = mfma16(axf[c], wih0[c], gr);
      gz = mfma16(axf[c], wih1[c], gz);
      gn = mfma16(axf[c], wih2[c], gn);
    }
    if (lt + 1 < TT) {
      int m = tid >> 6, k0 = (tid & 63) << 2;
      float4 v = *reinterpret_cast<const float4*>(
          x + ((size_t)(lt + 1) * BB + b0) * II + m * 256 + k0);
      ushort4 b;
      b.x = rne_bf16(v.x); b.y = rne_bf16(v.y);
      b.z = rne_bf16(v.z); b.w = rne_bf16(v.w);
      *reinterpret_cast<ushort4*>(&xbuf[nxt][SWZ(m, k0)]) = b;
    }
#pragma unroll
    for (int c = 0; c < 8; ++c) {
      ar = mfma16(ah[c], whh0[c], ar);
      az = mfma16(ah[c], whh1[c], az);
      an = mfma16(ah[c], whh2[c], an);
    }
#pragma unroll
    for (int q = 0; q < 4; ++q) {
      float r = sigm(ar[q] + gr[q] + bias_r);
      float zz = sigm(az[q] + gz[q] + bias_z);
      float nn = tanhfast(gn[q] + bihn + r * (an[q] + bhhn));
      float hq = (1.0f - zz) * nn + zz * h[q];
      h[q] = hq;
      hbuf[nxt][SWZ(g4 * 4 + q, j)] = rne_bf16(hq);
    }
    __syncthreads();
  }
#pragma unroll
  for (int q = 0; q < 4; ++q) hfin[g4 * 4 + q][j] = h[q];
  __syncthreads();
  float s = 0.0f;
#pragma unroll
  for (int i = 0; i < 4; ++i) {
    int k = lane + 64 * i;
    s += hfin[w][k] * Wout[k];
  }
#pragma unroll
  for (int off = 32; off > 0; off >>= 1) s += __shfl_xor(s, off, 64);
  if (lane == 0) out[b0 + w] = sigm(s + bout[0]);
}

extern "C" void kernel_launch(void* const* d_in, const int* in_sizes, int n_in,
                              void* d_out, int out_size, void* d_ws, size_t ws_size,
                              hipStream_t stream) {
  const float* x    = (const float*)d_in[0];
  const float* Wih  = (const float*)d_in[1];
  const float* Whh  = (const float*)d_in[2];
  const float* bih  = (const float*)d_in[3];
  const float* bhh  = (const float*)d_in[4];
  const float* Wout = (const float*)d_in[5];
  const float* bout = (const float*)d_in[6];
  float* out = (float*)d_out;

  const size_t HBYTES = (size_t)BB * HH * sizeof(float);           // 256 KB
  const size_t STEP_BYTES = (size_t)128 * 768 * sizeof(unsigned);  // 384 KB / t
  size_t gi_cap = ws_size > HBYTES ? ws_size - HBYTES : 0;
  long tc = (long)(gi_cap / STEP_BYTES);
  if (tc > TT) tc = TT;

  if (tc >= 32) {
    float* hchk = (float*)d_ws;
    unsigned int* gi = (unsigned int*)((char*)d_ws + HBYTES);
    for (int t0 = 0; t0 < TT; t0 += (int)tc) {
      int nt = (TT - t0) < (int)tc ? (TT - t0) : (int)tc;
      gi_gemm5<<<dim3(256), dim3(256), 0, stream>>>(
          x + (size_t)t0 * BB * II, Wih, bih, bhh, gi, nt * 16);
      gru_step4<<<dim3(128), dim3(256), 0, stream>>>(
          Whh, bhh, Wout, bout, gi, hchk, out, t0, nt);
    }
  } else {
    gru_fused_legacy<<<dim3(16), dim3(1024), 0, stream>>>(
        x, Wih, Whh, bih, bhh, Wout, bout, out);
  }
}